// Round 1
// baseline (334.624 us; speedup 1.0000x reference)
//
#include <hip/hip_runtime.h>

// ---------------------------------------------------------------------------
// EMLLocalMessageBlock on MI355X.
// Decomposition:
//   x@W1 = center@(W1a+W1c) + nbhd@(W1b-W1c) + rel@W1d + b1
//   update = wnbhd@(vW@oW)/mass + (vb@oW)*(sg/mass) + ob,  wnbhd = sum_n g_n*nbhd_n
// Scramble: nbhd[n2][c2] = shift_{f%9}[channel f/9], f = n2*128+c2 (torch reshape)
// ---------------------------------------------------------------------------

#define USHORT unsigned short

typedef __attribute__((ext_vector_type(8)))  __bf16 v8bf;
typedef __attribute__((ext_vector_type(8)))  USHORT v8u;
typedef __attribute__((ext_vector_type(16))) float  v16f;

__device__ __forceinline__ float bf2f(USHORT u) {
    unsigned v = ((unsigned)u) << 16; float f; __builtin_memcpy(&f, &v, 4); return f;
}
__device__ __forceinline__ USHORT f2bf(float f) {
    unsigned v; __builtin_memcpy(&v, &f, 4);
    v += 0x7FFFu + ((v >> 16) & 1u);            // RNE
    return (USHORT)(v >> 16);
}
__device__ __forceinline__ float gelu_exact(float x) {
    return 0.5f * x * (1.f + erff(x * 0.70710678118654752f));
}

// ---------------------------------------------------------------------------
// k_prep: fold weights. Layouts are pre-transposed for LDS b128 B-frag reads.
//   WnTg[n(256)][k(128)] = (W1b - W1c)[k][n]      (n<128 drive, else resistance)
//   WcTg[n(256)][k(128)] = (W1a + W1c)[k][n]
//   VTg [n(128)][k(128)] = (vW@oW)[k][n]
//   preg[9][256] = rel@W1d + b1 ;  vboWg[128] = vb@oW ;  w2g[256] = [dW2|rW2]
// ---------------------------------------------------------------------------
__global__ __launch_bounds__(256) void k_prep(
    const float* __restrict__ dW1, const float* __restrict__ db1,
    const float* __restrict__ rW1, const float* __restrict__ rb1,
    const float* __restrict__ rel, const float* __restrict__ dW2,
    const float* __restrict__ rW2, const float* __restrict__ vW,
    const float* __restrict__ vb,  const float* __restrict__ oW,
    USHORT* __restrict__ WnTg, USHORT* __restrict__ WcTg, USHORT* __restrict__ VTg,
    float* __restrict__ preg, float* __restrict__ vboWg, float* __restrict__ w2g)
{
    const int blk = blockIdx.x, t = threadIdx.x;
    if (blk < 64) {                       // vW@oW (transposed store)
        int idx = blk * 256 + t; int n = idx >> 7, k = idx & 127;
        float acc = 0.f;
        for (int j = 0; j < 128; ++j) acc += vW[k * 128 + j] * oW[j * 128 + n];
        VTg[n * 128 + k] = f2bf(acc);
    } else if (blk < 96) {                // folded W1 pieces
        for (int i = (blk - 64) * 256 + t; i < 32768; i += 8192) {
            int n = i >> 7, k = i & 127;
            float wa, wb, wc;
            if (n < 128) {
                wc = dW1[(256 + k) * 128 + n];
                wb = dW1[(128 + k) * 128 + n];
                wa = dW1[k * 128 + n];
            } else {
                int nn = n - 128;
                wc = rW1[(256 + k) * 128 + nn];
                wb = rW1[(128 + k) * 128 + nn];
                wa = rW1[k * 128 + nn];
            }
            WnTg[n * 128 + k] = f2bf(wb - wc);
            WcTg[n * 128 + k] = f2bf(wa + wc);
        }
    } else if (blk < 105) {               // rel@W1d + b1, per n2
        int n2 = blk - 96; int h = t;
        float acc;
        if (h < 128) {
            acc = db1[h];
            for (int r = 0; r < 8; ++r) acc += rel[n2 * 8 + r] * dW1[(384 + r) * 128 + h];
        } else {
            int hh = h - 128;
            acc = rb1[hh];
            for (int r = 0; r < 8; ++r) acc += rel[n2 * 8 + r] * rW1[(384 + r) * 128 + hh];
        }
        preg[n2 * 256 + h] = acc;
    } else {
        if (t < 128) {
            float acc = 0.f;
            for (int j = 0; j < 128; ++j) acc += vb[j] * oW[j * 128 + t];
            vboWg[t] = acc;
            w2g[t] = dW2[t];
            w2g[128 + t] = rW2[t];
        }
    }
}

// ---------------------------------------------------------------------------
// k_ln1: LayerNorm(tokens) -> bf16, one wave per pixel.
// ---------------------------------------------------------------------------
__global__ __launch_bounds__(256) void k_ln1(
    const float* __restrict__ tok, const float* __restrict__ g,
    const float* __restrict__ b, USHORT* __restrict__ nb)
{
    const int p = blockIdx.x * 4 + (threadIdx.x >> 6);
    const int lane = threadIdx.x & 63;
    const float2 x = ((const float2*)(tok + (size_t)p * 128))[lane];
    float s = x.x + x.y;
    for (int m = 1; m < 64; m <<= 1) s += __shfl_xor(s, m);
    const float mean = s * (1.f / 128.f);
    const float d0 = x.x - mean, d1 = x.y - mean;
    float q = d0 * d0 + d1 * d1;
    for (int m = 1; m < 64; m <<= 1) q += __shfl_xor(q, m);
    const float rstd = rsqrtf(q * (1.f / 128.f) + 1e-5f);
    const float2 gg = ((const float2*)g)[lane], bb = ((const float2*)b)[lane];
    const float o0 = d0 * rstd * gg.x + bb.x;
    const float o1 = d1 * rstd * gg.y + bb.y;
    ((unsigned*)nb)[(size_t)p * 64 + lane] =
        (unsigned)f2bf(o0) | ((unsigned)f2bf(o1) << 16);
}

// ---------------------------------------------------------------------------
// k_edge: 256 blocks, one image row (128 pixels) each. 512 threads = 8 waves.
// Wave w: Mgroup = w&3 (32-pixel rows), Nhalf = w>>2 (drive cols / res cols).
// MFMA 32x32x16 bf16; C/D: col=lane&31, row=(reg&3)+8*(reg>>2)+4*(lane>>5).
// LDS (dynamic, 141312 B):
//   buf0 [0,69632):       WcT/WnT [256][136] bf16 | phase2: upd[128][128] f32
//   buf1 [69632,104448):  As[128][136] bf16       | phase2: Wb (bf16 wnbhd)
//   buf2 [104448,139264): pre[9][256]f32 + w2[256]| phase2: VT[128][136] bf16
//   buf3 [139264,141312): dsum|rsum|gate|sg  (phase2: dsum=1/mass, rsum=sg/mass)
// ---------------------------------------------------------------------------
__global__ __launch_bounds__(512, 2) void k_edge(
    const float* __restrict__ tok, const float* __restrict__ ln2g,
    const float* __restrict__ ln2b, const USHORT* __restrict__ nb,
    const USHORT* __restrict__ WnTg, const USHORT* __restrict__ WcTg,
    const USHORT* __restrict__ VTg, const float* __restrict__ preg,
    const float* __restrict__ vboWg, const float* __restrict__ w2g,
    const float* __restrict__ db2p, const float* __restrict__ rb2p,
    const float* __restrict__ gmp, const float* __restrict__ lmp,
    const float* __restrict__ bip, const float* __restrict__ obp,
    float* __restrict__ out)
{
    extern __shared__ char smem[];
    USHORT* Wsh  = (USHORT*)smem;                  // weights [256][136]
    float*  upd  = (float*)smem;                   // phase2 alias [128][128]
    USHORT* As   = (USHORT*)(smem + 69632);        // A tile / Wb [128][136]
    float*  preL = (float*)(smem + 104448);        // 2304 f32
    float*  w2L  = preL + 2304;                    // 256 f32
    USHORT* VTl  = (USHORT*)(smem + 104448);       // phase2 alias [128][136]
    float*  dsum = (float*)(smem + 139264);
    float*  rsum = dsum + 128;
    float*  gateL= dsum + 256;
    float*  sgL  = dsum + 384;

    const int tid = threadIdx.x;
    const int lane = tid & 63, wave = tid >> 6, hi = lane >> 5, l31 = lane & 31;
    const int Mg = wave & 3, Nh = wave >> 2;
    const int blk = blockIdx.x, bI = blk >> 7, y = blk & 127;
    const int p0 = blk << 7;

    // ---- phase 0: center GEMM (cpart kept in registers) ----
    for (int i = tid; i < 4096; i += 512) {
        int n = i >> 4, kv = i & 15;
        *(v8u*)(Wsh + n * 136 + kv * 8) = *(const v8u*)(WcTg + n * 128 + kv * 8);
    }
    for (int i = tid; i < 2048; i += 512) {
        int x = i >> 4, kv = i & 15;
        *(v8u*)(As + x * 136 + kv * 8) =
            *(const v8u*)(nb + (size_t)(p0 + x) * 128 + kv * 8);
    }
    __syncthreads();

    v16f cp[4];
    #pragma unroll
    for (int t2 = 0; t2 < 4; ++t2)
        for (int e = 0; e < 16; ++e) cp[t2][e] = 0.f;
    #pragma unroll
    for (int ks = 0; ks < 8; ++ks) {
        v8bf a = *(const v8bf*)(As + (Mg * 32 + l31) * 136 + ks * 16 + hi * 8);
        #pragma unroll
        for (int t2 = 0; t2 < 4; ++t2) {
            v8bf bv = *(const v8bf*)(Wsh + (Nh * 128 + t2 * 32 + l31) * 136 + ks * 16 + hi * 8);
            cp[t2] = __builtin_amdgcn_mfma_f32_32x32x16_bf16(a, bv, cp[t2], 0, 0, 0);
        }
    }
    __syncthreads();

    // ---- stage folded neighbor weights + consts ----
    for (int i = tid; i < 4096; i += 512) {
        int n = i >> 4, kv = i & 15;
        *(v8u*)(Wsh + n * 136 + kv * 8) = *(const v8u*)(WnTg + n * 128 + kv * 8);
    }
    for (int i = tid; i < 2304; i += 512) preL[i] = preg[i];
    if (tid < 256) w2L[tid] = w2g[tid];
    if (tid < 128) sgL[tid] = 0.f;
    __syncthreads();

    const int c2g = tid & 127, xb = tid >> 7;
    const float gmv = gmp[0], lmv = lmp[0], biv = bip[0];
    const float b2v = Nh ? rb2p[0] : db2p[0];

    float wn[32];
    #pragma unroll
    for (int i = 0; i < 32; ++i) wn[i] = 0.f;

    for (int n2 = 0; n2 < 9; ++n2) {
        // gather A tile: As[x][c2] = nbhd (scrambled); f = n2*128+c2, c=f/9, n=f%9
        {
            int f = n2 * 128 + c2g;
            int c = f / 9;
            int n = f - 9 * c;
            int dy = n / 3 - 1;
            int dx = (n - 3 * (n / 3)) - 1;
            int sy = y + dy;
            bool rok = ((unsigned)sy) < 128u;
            const USHORT* srow = nb + ((size_t)((bI * 128 + (rok ? sy : 0)) * 128)) * 128 + c;
            #pragma unroll
            for (int j = 0; j < 32; ++j) {
                int x = xb + j * 4;
                int sx = x + dx;
                USHORT v = 0;
                if (rok && ((unsigned)sx) < 128u) v = srow[(size_t)sx * 128];
                As[x * 136 + c2g] = v;
            }
        }
        __syncthreads();

        // GEMM: acc = cpart + A_{n2}@Wn
        v16f acc[4];
        #pragma unroll
        for (int t2 = 0; t2 < 4; ++t2) acc[t2] = cp[t2];
        #pragma unroll
        for (int ks = 0; ks < 8; ++ks) {
            v8bf a = *(const v8bf*)(As + (Mg * 32 + l31) * 136 + ks * 16 + hi * 8);
            #pragma unroll
            for (int t2 = 0; t2 < 4; ++t2) {
                v8bf bv = *(const v8bf*)(Wsh + (Nh * 128 + t2 * 32 + l31) * 136 + ks * 16 + hi * 8);
                acc[t2] = __builtin_amdgcn_mfma_f32_32x32x16_bf16(a, bv, acc[t2], 0, 0, 0);
            }
        }

        // epilogue: gelu(acc + pre) dot w2 -> per-pixel drive/resistance
        float partial[16];
        #pragma unroll
        for (int r = 0; r < 16; ++r) partial[r] = 0.f;
        #pragma unroll
        for (int t2 = 0; t2 < 4; ++t2) {
            int col = Nh * 128 + t2 * 32 + l31;
            float pv = preL[n2 * 256 + col];
            float wv = w2L[col];
            #pragma unroll
            for (int r = 0; r < 16; ++r)
                partial[r] += gelu_exact(acc[t2][r] + pv) * wv;
        }
        #pragma unroll
        for (int m = 1; m < 32; m <<= 1) {
            #pragma unroll
            for (int r = 0; r < 16; ++r) partial[r] += __shfl_xor(partial[r], m);
        }
        if (l31 == 0) {
            float* tgt = Nh ? rsum : dsum;
            #pragma unroll
            for (int r = 0; r < 16; ++r) {
                int row = (r & 3) + 8 * (r >> 2) + 4 * hi;
                tgt[Mg * 32 + row] = partial[r] + b2v;
            }
        }
        __syncthreads();

        if (tid < 128) {
            float d = dsum[tid], rr = rsum[tid];
            float sp = fmaxf(rr, 0.f) + log1pf(expf(-fabsf(rr)));
            float e = gmv * d / (lmv * sp + 1e-6f) + biv;
            e = fminf(fmaxf(e, -3.f), 3.f);
            float gt = 1.f / (1.f + expf(-e));
            gateL[tid] = gt;
            sgL[tid] += gt;
        }
        __syncthreads();

        // wnbhd += gate * A_{n2}  (A still resident in LDS)
        {
            int p = tid >> 2, cb = (tid & 3) * 32;
            float gt = gateL[p];
            const USHORT* rp = As + p * 136 + cb;
            #pragma unroll
            for (int v = 0; v < 4; ++v) {
                v8u pk = *(const v8u*)(rp + v * 8);
                #pragma unroll
                for (int e = 0; e < 8; ++e) wn[v * 8 + e] += gt * bf2f(pk[e]);
            }
        }
        __syncthreads();
    }

    // ---- phase 2: update = wnbhd@(vW@oW)/mass + vboW*(sg/mass) + ob ----
    {
        int p = tid >> 2, cb = (tid & 3) * 32;
        #pragma unroll
        for (int v = 0; v < 4; ++v) {
            v8u pk;
            #pragma unroll
            for (int e = 0; e < 8; ++e) pk[e] = f2bf(wn[v * 8 + e]);
            *(v8u*)(As + p * 136 + cb + v * 8) = pk;
        }
    }
    for (int i = tid; i < 2048; i += 512) {
        int n = i >> 4, kv = i & 15;
        *(v8u*)(VTl + n * 136 + kv * 8) = *(const v8u*)(VTg + n * 128 + kv * 8);
    }
    if (tid < 128) {
        float s = sgL[tid];
        float m = fmaxf(s, 1e-6f);
        dsum[tid] = 1.f / m;     // 1/mass
        rsum[tid] = s / m;       // sg/mass
    }
    __syncthreads();

    v16f a3[2];
    #pragma unroll
    for (int t2 = 0; t2 < 2; ++t2)
        for (int e = 0; e < 16; ++e) a3[t2][e] = 0.f;
    #pragma unroll
    for (int ks = 0; ks < 8; ++ks) {
        v8bf a = *(const v8bf*)(As + (Mg * 32 + l31) * 136 + ks * 16 + hi * 8);
        #pragma unroll
        for (int t2 = 0; t2 < 2; ++t2) {
            v8bf bv = *(const v8bf*)(VTl + (Nh * 64 + t2 * 32 + l31) * 136 + ks * 16 + hi * 8);
            a3[t2] = __builtin_amdgcn_mfma_f32_32x32x16_bf16(a, bv, a3[t2], 0, 0, 0);
        }
    }
    #pragma unroll
    for (int t2 = 0; t2 < 2; ++t2) {
        int col = Nh * 64 + t2 * 32 + l31;
        float vbw = vboWg[col], obv = obp[col];
        #pragma unroll
        for (int r = 0; r < 16; ++r) {
            int row = (r & 3) + 8 * (r >> 2) + 4 * hi;
            int p = Mg * 32 + row;
            upd[p * 128 + col] = a3[t2][r] * dsum[p] + vbw * rsum[p] + obv;
        }
    }
    __syncthreads();

    // ---- fused LN2(tokens + update) ----
    const float g20 = ln2g[lane], g21 = ln2g[lane + 64];
    const float b20 = ln2b[lane], b21 = ln2b[lane + 64];
    for (int q = 0; q < 16; ++q) {
        int p = wave * 16 + q;
        size_t gp = (size_t)(p0 + p) * 128;
        float x0 = tok[gp + lane]      + upd[p * 128 + lane];
        float x1 = tok[gp + lane + 64] + upd[p * 128 + lane + 64];
        float s = x0 + x1;
        for (int m = 1; m < 64; m <<= 1) s += __shfl_xor(s, m);
        float mean = s * (1.f / 128.f);
        float d0 = x0 - mean, d1 = x1 - mean;
        float qq = d0 * d0 + d1 * d1;
        for (int m = 1; m < 64; m <<= 1) qq += __shfl_xor(qq, m);
        float rstd = rsqrtf(qq * (1.f / 128.f) + 1e-5f);
        out[gp + lane]      = d0 * rstd * g20 + b20;
        out[gp + lane + 64] = d1 * rstd * g21 + b21;
    }
}

// ---------------------------------------------------------------------------
extern "C" void kernel_launch(void* const* d_in, const int* in_sizes, int n_in,
                              void* d_out, int out_size, void* d_ws, size_t ws_size,
                              hipStream_t stream) {
    const float* tok  = (const float*)d_in[0];
    const float* ln1g = (const float*)d_in[1];
    const float* ln1b = (const float*)d_in[2];
    const float* ln2g = (const float*)d_in[3];
    const float* ln2b = (const float*)d_in[4];
    const float* rel  = (const float*)d_in[5];
    const float* dW1  = (const float*)d_in[6];
    const float* db1  = (const float*)d_in[7];
    const float* dW2  = (const float*)d_in[8];
    const float* db2  = (const float*)d_in[9];
    const float* rW1  = (const float*)d_in[10];
    const float* rb1  = (const float*)d_in[11];
    const float* rW2  = (const float*)d_in[12];
    const float* rb2  = (const float*)d_in[13];
    const float* vW   = (const float*)d_in[14];
    const float* vb   = (const float*)d_in[15];
    const float* oW   = (const float*)d_in[16];
    const float* ob   = (const float*)d_in[17];
    const float* gm   = (const float*)d_in[18];
    const float* lm   = (const float*)d_in[19];
    const float* bi   = (const float*)d_in[20];
    float* out = (float*)d_out;

    // workspace carve (~8.6 MB, all 256-aligned)
    char* w = (char*)d_ws;
    USHORT* norm = (USHORT*)w; w += 8388608;   // [32768][128] bf16
    USHORT* WnTg = (USHORT*)w; w += 65536;     // [256][128] bf16
    USHORT* WcTg = (USHORT*)w; w += 65536;     // [256][128] bf16
    USHORT* VTg  = (USHORT*)w; w += 32768;     // [128][128] bf16
    float*  preg = (float*)w;  w += 9216;      // [9][256] f32
    float*  vboWg= (float*)w;  w += 1024;      // [128] f32
    float*  w2g  = (float*)w;  w += 1024;      // [256] f32

    hipFuncSetAttribute((const void*)k_edge,
                        hipFuncAttributeMaxDynamicSharedMemorySize, 141312);

    hipLaunchKernelGGL(k_prep, dim3(106), dim3(256), 0, stream,
                       dW1, db1, rW1, rb1, rel, dW2, rW2, vW, vb, oW,
                       WnTg, WcTg, VTg, preg, vboWg, w2g);
    hipLaunchKernelGGL(k_ln1, dim3(8192), dim3(256), 0, stream,
                       tok, ln1g, ln1b, norm);
    hipLaunchKernelGGL(k_edge, dim3(256), dim3(512), 141312, stream,
                       tok, ln2g, ln2b, norm, WnTg, WcTg, VTg, preg, vboWg, w2g,
                       db2, rb2, gm, lm, bi, ob, out);
}

// Round 2
// 223.341 us; speedup vs baseline: 1.4983x; 1.4983x over previous
//
#include <hip/hip_runtime.h>

// ---------------------------------------------------------------------------
// EMLLocalMessageBlock on MI355X — round 2.
// K-permutation: slot k' = 16*r + t  <->  c2 = r + 9t (r = c2 mod 9), t<len(r);
// per (n2, r): shift n = (2*n2 + r) % 9, channels c = c0 + t, c0 = (n2*128+r)/9.
// This is n2-independent on the weight side -> Wn/VoW permuted once in k_prep;
// slots with c2 >= 128 carry zero weight rows (A-side garbage is nulled).
// ---------------------------------------------------------------------------

#define USHORT unsigned short
#define AS_W 168   // As row stride (elements), 336 B: 16B-aligned
#define W_W  160   // Wsh row stride (elements), 320 B: 2-way-free for b128

typedef __attribute__((ext_vector_type(8)))  __bf16 v8bf;
typedef __attribute__((ext_vector_type(8)))  USHORT v8u;
typedef __attribute__((ext_vector_type(16))) float  v16f;

__device__ __forceinline__ float bflo(unsigned u) {
    unsigned v = u << 16; float f; __builtin_memcpy(&f, &v, 4); return f;
}
__device__ __forceinline__ float bfhi(unsigned u) {
    unsigned v = u & 0xffff0000u; float f; __builtin_memcpy(&f, &v, 4); return f;
}
__device__ __forceinline__ USHORT f2bf(float f) {
    unsigned v; __builtin_memcpy(&v, &f, 4);
    v += 0x7FFFu + ((v >> 16) & 1u);
    return (USHORT)(v >> 16);
}

// ---------------------------------------------------------------------------
// k_prep
// ---------------------------------------------------------------------------
__global__ __launch_bounds__(256) void k_prep(
    const float* __restrict__ dW1, const float* __restrict__ db1,
    const float* __restrict__ rW1, const float* __restrict__ rb1,
    const float* __restrict__ rel, const float* __restrict__ dW2,
    const float* __restrict__ rW2, const float* __restrict__ vW,
    const float* __restrict__ vb,  const float* __restrict__ oW,
    USHORT* __restrict__ WnTg, USHORT* __restrict__ WcTg, USHORT* __restrict__ VTg,
    float* __restrict__ preg, float* __restrict__ vboWg, float* __restrict__ w2g)
{
    const int blk = blockIdx.x, t = threadIdx.x;
    if (blk < 72) {                       // VTg_p [128][144] = perm(vW@oW)^T
        int idx = blk * 256 + t;
        int n = ((idx >> 4) * 7282) >> 16;          // idx/144
        int k = idx - n * 144;
        int r = k >> 4, tt = k & 15, c2 = r + 9 * tt;
        float acc = 0.f;
        if (c2 < 128)
            for (int j = 0; j < 128; ++j) acc += vW[c2 * 128 + j] * oW[j * 128 + n];
        VTg[idx] = f2bf(acc);
    } else if (blk < 216) {               // WnTg_p [256][144] = perm(W1b-W1c)^T
        int idx = (blk - 72) * 256 + t;
        int n = ((idx >> 4) * 7282) >> 16;
        int k = idx - n * 144;
        int r = k >> 4, tt = k & 15, c2 = r + 9 * tt;
        int col = n & 127;
        const float* W = (n < 128) ? dW1 : rW1;
        float val = 0.f;
        if (c2 < 128) val = W[(128 + c2) * 128 + col] - W[(256 + c2) * 128 + col];
        WnTg[idx] = f2bf(val);
    } else if (blk < 344) {               // WcTg [256][128] = (W1a+W1c)^T
        int idx = (blk - 216) * 256 + t;
        int n = idx >> 7, c = idx & 127, col = n & 127;
        const float* W = (n < 128) ? dW1 : rW1;
        WcTg[idx] = f2bf(W[c * 128 + col] + W[(256 + c) * 128 + col]);
    } else if (blk < 353) {               // preg[9][256] = rel@W1d + b1
        int n2 = blk - 344; int h = t;
        float acc;
        if (h < 128) {
            acc = db1[h];
            for (int r = 0; r < 8; ++r) acc += rel[n2 * 8 + r] * dW1[(384 + r) * 128 + h];
        } else {
            int hh = h - 128;
            acc = rb1[hh];
            for (int r = 0; r < 8; ++r) acc += rel[n2 * 8 + r] * rW1[(384 + r) * 128 + hh];
        }
        preg[n2 * 256 + h] = acc;
    } else {
        if (t < 128) {
            float acc = 0.f;
            for (int j = 0; j < 128; ++j) acc += vb[j] * oW[j * 128 + t];
            vboWg[t] = acc;
            w2g[t] = dW2[t];
            w2g[128 + t] = rW2[t];
        }
    }
}

// ---------------------------------------------------------------------------
// k_ln1: LayerNorm(tokens) -> bf16
// ---------------------------------------------------------------------------
__global__ __launch_bounds__(256) void k_ln1(
    const float* __restrict__ tok, const float* __restrict__ g,
    const float* __restrict__ b, USHORT* __restrict__ nb)
{
    const int p = blockIdx.x * 4 + (threadIdx.x >> 6);
    const int lane = threadIdx.x & 63;
    const float2 x = ((const float2*)(tok + (size_t)p * 128))[lane];
    float s = x.x + x.y;
    for (int m = 1; m < 64; m <<= 1) s += __shfl_xor(s, m);
    const float mean = s * (1.f / 128.f);
    const float d0 = x.x - mean, d1 = x.y - mean;
    float q = d0 * d0 + d1 * d1;
    for (int m = 1; m < 64; m <<= 1) q += __shfl_xor(q, m);
    const float rstd = rsqrtf(q * (1.f / 128.f) + 1e-5f);
    const float2 gg = ((const float2*)g)[lane], bb = ((const float2*)b)[lane];
    const float o0 = d0 * rstd * gg.x + bb.x;
    const float o1 = d1 * rstd * gg.y + bb.y;
    ((unsigned*)nb)[(size_t)p * 64 + lane] =
        (unsigned)f2bf(o0) | ((unsigned)f2bf(o1) << 16);
}

// ---------------------------------------------------------------------------
// gather one n2 A-tile into LDS (permuted-K layout), coalesced global reads
// ---------------------------------------------------------------------------
__device__ __forceinline__ void gather_tile(
    USHORT* __restrict__ Ash, const USHORT* __restrict__ nb,
    int n2, int y, int bI, int tid)
{
    const int x = tid >> 2, q = tid & 3;
    #pragma unroll
    for (int r = 0; r < 9; ++r) {
        int u = 2 * n2 + r;
        int n = (u >= 18) ? (u - 18) : ((u >= 9) ? (u - 9) : u);
        int v = n2 * 128 + r;
        int c0 = (v * 7282) >> 16;                 // v/9
        int dyq = (n * 22) >> 6;                   // n/3
        int dx = n - 3 * dyq - 1;
        int dy = dyq - 1;
        int sy = y + dy, sx = x + dx;
        bool ok = ((unsigned)sy < 128u) && ((unsigned)sx < 128u);
        int e0 = (c0 & ~1) + 4 * q;
        size_t gidx = ((size_t)((bI * 128 + (ok ? sy : 0)) * 128 + (ok ? sx : 0))) * 128 + e0;
        const unsigned* gp = (const unsigned*)nb + (gidx >> 1);
        unsigned dw0 = gp[0], dw1 = gp[1];
        unsigned nxt = (unsigned)__shfl_down((int)dw0, 1);   // only feeds slot15 (zero-wt)
        unsigned o0, o1;
        if (c0 & 1) { o0 = (dw0 >> 16) | (dw1 << 16); o1 = (dw1 >> 16) | (nxt << 16); }
        else        { o0 = dw0;                       o1 = dw1; }
        if (!ok) { o0 = 0u; o1 = 0u; }
        *(uint2*)(Ash + x * AS_W + 16 * r + 4 * q) = make_uint2(o0, o1);
    }
}

// ---------------------------------------------------------------------------
// k_edge: 256 blocks (one image row each, y-swizzled for XCD L2 bands),
// 512 threads = 8 waves = 2(M) x 4(N) grid, each wave 64x64 (2x2 of 32x32).
// ---------------------------------------------------------------------------
__global__ __launch_bounds__(512, 2) void k_edge(
    const float* __restrict__ tok, const float* __restrict__ ln2g,
    const float* __restrict__ ln2b, const USHORT* __restrict__ nb,
    const USHORT* __restrict__ WnTg, const USHORT* __restrict__ WcTg,
    const USHORT* __restrict__ VTg, const float* __restrict__ preg,
    const float* __restrict__ vboWg, const float* __restrict__ w2g,
    const float* __restrict__ db2p, const float* __restrict__ rb2p,
    const float* __restrict__ gmp, const float* __restrict__ lmp,
    const float* __restrict__ bip, const float* __restrict__ obp,
    float* __restrict__ out)
{
    extern __shared__ char smem[];
    USHORT* Wsh  = (USHORT*)smem;                    // [256][160] = 81920 B
    USHORT* Ash  = (USHORT*)(smem + 81920);          // [128][168] = 43008 B
    float*  preL = (float*)(smem + 124928);          // [9][256]   = 9216 B
    float*  w2L  = (float*)(smem + 134144);          // 1024 B
    float*  dsum = (float*)(smem + 135168);          // 512 B
    float*  rsum = (float*)(smem + 135680);
    float*  gateL= (float*)(smem + 136192);
    float*  sgL  = (float*)(smem + 136704);          // total 137216

    const int tid = threadIdx.x;
    const int lane = tid & 63, wave = tid >> 6, hi = lane >> 5, l31 = lane & 31;
    const int mw = wave & 1, nw = wave >> 1;
    const int blk = blockIdx.x;
    const int bI = blk >> 7;
    const int y = ((blk & 7) << 4) | ((blk >> 3) & 15);   // XCD band swizzle
    const int p0 = (bI * 128 + y) * 128;

    // ---- stage WcT + center A + consts ----
    for (int i = tid; i < 4096; i += 512) {
        int n = i >> 4, kv = i & 15;
        *(v8u*)(Wsh + n * W_W + kv * 8) = *(const v8u*)(WcTg + n * 128 + kv * 8);
    }
    for (int i = tid; i < 2048; i += 512) {
        int x = i >> 4, kv = i & 15;
        *(v8u*)(Ash + x * AS_W + kv * 8) = *(const v8u*)(nb + (size_t)(p0 + x) * 128 + kv * 8);
    }
    for (int i = tid; i < 2304; i += 512) preL[i] = preg[i];
    if (tid < 256) w2L[tid] = w2g[tid];
    if (tid < 128) { dsum[tid] = 0.f; rsum[tid] = 0.f; sgL[tid] = 0.f; }
    __syncthreads();

    // ---- phase 0: center GEMM (K=128 natural channels) ----
    v16f cp[2][2];
    #pragma unroll
    for (int a = 0; a < 2; ++a)
        for (int b = 0; b < 2; ++b)
            for (int e = 0; e < 16; ++e) cp[a][b][e] = 0.f;
    #pragma unroll
    for (int ks = 0; ks < 8; ++ks) {
        v8bf af0 = *(const v8bf*)(Ash + (mw * 64 + l31) * AS_W + ks * 16 + hi * 8);
        v8bf af1 = *(const v8bf*)(Ash + (mw * 64 + 32 + l31) * AS_W + ks * 16 + hi * 8);
        v8bf bf0 = *(const v8bf*)(Wsh + (nw * 64 + l31) * W_W + ks * 16 + hi * 8);
        v8bf bf1 = *(const v8bf*)(Wsh + (nw * 64 + 32 + l31) * W_W + ks * 16 + hi * 8);
        cp[0][0] = __builtin_amdgcn_mfma_f32_32x32x16_bf16(af0, bf0, cp[0][0], 0, 0, 0);
        cp[0][1] = __builtin_amdgcn_mfma_f32_32x32x16_bf16(af0, bf1, cp[0][1], 0, 0, 0);
        cp[1][0] = __builtin_amdgcn_mfma_f32_32x32x16_bf16(af1, bf0, cp[1][0], 0, 0, 0);
        cp[1][1] = __builtin_amdgcn_mfma_f32_32x32x16_bf16(af1, bf1, cp[1][1], 0, 0, 0);
    }
    __syncthreads();

    // ---- stage permuted Wn (overwrites WcT) + first gather ----
    for (int i = tid; i < 4608; i += 512) {
        int n = (i * 3641) >> 16;                 // i/18
        int kv = i - n * 18;
        *(v8u*)(Wsh + n * W_W + kv * 8) = *(const v8u*)(WnTg + n * 144 + kv * 8);
    }
    gather_tile(Ash, nb, 0, y, bI, tid);

    const float gmv = gmp[0], lmv = lmp[0], biv = bip[0];
    const float db2v = db2p[0], rb2v = rb2p[0];

    float wn[36];
    #pragma unroll
    for (int i = 0; i < 36; ++i) wn[i] = 0.f;

    for (int n2 = 0; n2 < 9; ++n2) {
        __syncthreads();
        // ---- edge GEMM: acc = cp + A_{n2} @ Wn_p (K'=144) ----
        v16f acc[2][2];
        #pragma unroll
        for (int a = 0; a < 2; ++a)
            for (int b = 0; b < 2; ++b) acc[a][b] = cp[a][b];
        #pragma unroll
        for (int ks = 0; ks < 9; ++ks) {
            v8bf af0 = *(const v8bf*)(Ash + (mw * 64 + l31) * AS_W + ks * 16 + hi * 8);
            v8bf af1 = *(const v8bf*)(Ash + (mw * 64 + 32 + l31) * AS_W + ks * 16 + hi * 8);
            v8bf bf0 = *(const v8bf*)(Wsh + (nw * 64 + l31) * W_W + ks * 16 + hi * 8);
            v8bf bf1 = *(const v8bf*)(Wsh + (nw * 64 + 32 + l31) * W_W + ks * 16 + hi * 8);
            acc[0][0] = __builtin_amdgcn_mfma_f32_32x32x16_bf16(af0, bf0, acc[0][0], 0, 0, 0);
            acc[0][1] = __builtin_amdgcn_mfma_f32_32x32x16_bf16(af0, bf1, acc[0][1], 0, 0, 0);
            acc[1][0] = __builtin_amdgcn_mfma_f32_32x32x16_bf16(af1, bf0, acc[1][0], 0, 0, 0);
            acc[1][1] = __builtin_amdgcn_mfma_f32_32x32x16_bf16(af1, bf1, acc[1][1], 0, 0, 0);
        }
        // ---- epilogue: gelu(h)·w2, reduce over cols, atomic into dsum/rsum ----
        #pragma unroll
        for (int mt = 0; mt < 2; ++mt) {
            float part[16];
            #pragma unroll
            for (int rr = 0; rr < 16; ++rr) part[rr] = 0.f;
            #pragma unroll
            for (int nt = 0; nt < 2; ++nt) {
                int col = nw * 64 + nt * 32 + l31;
                float pv = preL[n2 * 256 + col];
                float wv = w2L[col];
                #pragma unroll
                for (int rr = 0; rr < 16; ++rr) {
                    float h = acc[mt][nt][rr] + pv;
                    float sg = __builtin_amdgcn_rcpf(1.f + __expf(-1.702f * h));
                    part[rr] += h * sg * wv;
                }
            }
            #pragma unroll
            for (int m = 1; m < 32; m <<= 1) {
                #pragma unroll
                for (int rr = 0; rr < 16; ++rr) part[rr] += __shfl_xor(part[rr], m);
            }
            if (l31 == 0) {
                float* tgt = (nw < 2) ? dsum : rsum;
                #pragma unroll
                for (int rr = 0; rr < 16; ++rr) {
                    int row = mw * 64 + mt * 32 + (rr & 3) + 8 * (rr >> 2) + 4 * hi;
                    atomicAdd(&tgt[row], part[rr]);
                }
            }
        }
        __syncthreads();
        // ---- gate ----
        if (tid < 128) {
            float d = dsum[tid] + db2v, rr = rsum[tid] + rb2v;
            float sp = fmaxf(rr, 0.f) + log1pf(__expf(-fabsf(rr)));
            float e = gmv * d / (lmv * sp + 1e-6f) + biv;
            e = fminf(fmaxf(e, -3.f), 3.f);
            float gt = 1.f / (1.f + __expf(-e));
            gateL[tid] = gt; sgL[tid] += gt;
            dsum[tid] = 0.f; rsum[tid] = 0.f;
        }
        __syncthreads();
        // ---- wnbhd += gate * A_{n2} (k'-slot space) ----
        {
            int x = tid >> 2, q = tid & 3;
            float gt = gateL[x];
            const USHORT* rp = Ash + x * AS_W + q * 36;
            #pragma unroll
            for (int j = 0; j < 9; ++j) {
                uint2 pk = *(const uint2*)(rp + 4 * j);
                wn[4 * j + 0] += gt * bflo(pk.x);
                wn[4 * j + 1] += gt * bfhi(pk.x);
                wn[4 * j + 2] += gt * bflo(pk.y);
                wn[4 * j + 3] += gt * bfhi(pk.y);
            }
        }
        __syncthreads();
        if (n2 < 8) gather_tile(Ash, nb, n2 + 1, y, bI, tid);
    }

    // ---- phase 2: pack wnbhd, stage VT_p, message GEMM, upd, LN2 ----
    {
        int x = tid >> 2, q = tid & 3;
        USHORT* wp = Ash + x * AS_W + q * 36;
        #pragma unroll
        for (int j = 0; j < 9; ++j) {
            unsigned lo = (unsigned)f2bf(wn[4 * j + 0]) | ((unsigned)f2bf(wn[4 * j + 1]) << 16);
            unsigned h2 = (unsigned)f2bf(wn[4 * j + 2]) | ((unsigned)f2bf(wn[4 * j + 3]) << 16);
            *(uint2*)(wp + 4 * j) = make_uint2(lo, h2);
        }
    }
    for (int i = tid; i < 2304; i += 512) {
        int n = (i * 3641) >> 16;
        int kv = i - n * 18;
        *(v8u*)(Wsh + n * W_W + kv * 8) = *(const v8u*)(VTg + n * 144 + kv * 8);
    }
    if (tid < 128) {
        float s = sgL[tid];
        float m = fmaxf(s, 1e-6f);
        dsum[tid] = 1.f / m;     // 1/mass
        rsum[tid] = s / m;       // sg/mass
    }
    __syncthreads();

    v16f a3[2];
    #pragma unroll
    for (int a = 0; a < 2; ++a)
        for (int e = 0; e < 16; ++e) a3[a][e] = 0.f;
    #pragma unroll
    for (int ks = 0; ks < 9; ++ks) {
        v8bf bf0 = *(const v8bf*)(Wsh + (nw * 32 + l31) * W_W + ks * 16 + hi * 8);
        v8bf af0 = *(const v8bf*)(Ash + (mw * 64 + l31) * AS_W + ks * 16 + hi * 8);
        v8bf af1 = *(const v8bf*)(Ash + (mw * 64 + 32 + l31) * AS_W + ks * 16 + hi * 8);
        a3[0] = __builtin_amdgcn_mfma_f32_32x32x16_bf16(af0, bf0, a3[0], 0, 0, 0);
        a3[1] = __builtin_amdgcn_mfma_f32_32x32x16_bf16(af1, bf0, a3[1], 0, 0, 0);
    }
    __syncthreads();

    float* updF = (float*)smem;
    {
        int colc = nw * 32 + l31;
        float vbw = vboWg[colc], obv = obp[colc];
        #pragma unroll
        for (int mt = 0; mt < 2; ++mt) {
            #pragma unroll
            for (int rr = 0; rr < 16; ++rr) {
                int row = mw * 64 + mt * 32 + (rr & 3) + 8 * (rr >> 2) + 4 * hi;
                updF[row * 128 + colc] = a3[mt][rr] * dsum[row] + vbw * rsum[row] + obv;
            }
        }
    }
    __syncthreads();

    const float g20 = ln2g[lane], g21 = ln2g[lane + 64];
    const float b20 = ln2b[lane], b21 = ln2b[lane + 64];
    for (int q2 = 0; q2 < 16; ++q2) {
        int p = wave * 16 + q2;
        size_t gp = (size_t)(p0 + p) * 128;
        float x0 = tok[gp + lane]      + updF[p * 128 + lane];
        float x1 = tok[gp + lane + 64] + updF[p * 128 + lane + 64];
        float s = x0 + x1;
        for (int m = 1; m < 64; m <<= 1) s += __shfl_xor(s, m);
        float mean = s * (1.f / 128.f);
        float d0 = x0 - mean, d1 = x1 - mean;
        float qq = d0 * d0 + d1 * d1;
        for (int m = 1; m < 64; m <<= 1) qq += __shfl_xor(qq, m);
        float rstd = rsqrtf(qq * (1.f / 128.f) + 1e-5f);
        out[gp + lane]      = d0 * rstd * g20 + b20;
        out[gp + lane + 64] = d1 * rstd * g21 + b21;
    }
}

// ---------------------------------------------------------------------------
extern "C" void kernel_launch(void* const* d_in, const int* in_sizes, int n_in,
                              void* d_out, int out_size, void* d_ws, size_t ws_size,
                              hipStream_t stream) {
    const float* tok  = (const float*)d_in[0];
    const float* ln1g = (const float*)d_in[1];
    const float* ln1b = (const float*)d_in[2];
    const float* ln2g = (const float*)d_in[3];
    const float* ln2b = (const float*)d_in[4];
    const float* rel  = (const float*)d_in[5];
    const float* dW1  = (const float*)d_in[6];
    const float* db1  = (const float*)d_in[7];
    const float* dW2  = (const float*)d_in[8];
    const float* db2  = (const float*)d_in[9];
    const float* rW1  = (const float*)d_in[10];
    const float* rb1  = (const float*)d_in[11];
    const float* rW2  = (const float*)d_in[12];
    const float* rb2  = (const float*)d_in[13];
    const float* vW   = (const float*)d_in[14];
    const float* vb   = (const float*)d_in[15];
    const float* oW   = (const float*)d_in[16];
    const float* ob   = (const float*)d_in[17];
    const float* gm   = (const float*)d_in[18];
    const float* lm   = (const float*)d_in[19];
    const float* bi   = (const float*)d_in[20];
    float* out = (float*)d_out;

    char* w = (char*)d_ws;
    USHORT* norm = (USHORT*)w; w += 8388608;   // [32768][128] bf16 (gather may
                                               //  over-read 2 elems into WnTg: finite)
    USHORT* WnTg = (USHORT*)w; w += 73728;     // [256][144] bf16, permuted+zero-pad
    USHORT* WcTg = (USHORT*)w; w += 65536;     // [256][128] bf16
    USHORT* VTg  = (USHORT*)w; w += 36864;     // [128][144] bf16, permuted+zero-pad
    float*  preg = (float*)w;  w += 9216;      // [9][256] f32
    float*  vboWg= (float*)w;  w += 512;       // [128] f32
    float*  w2g  = (float*)w;  w += 1024;      // [256] f32

    hipFuncSetAttribute((const void*)k_edge,
                        hipFuncAttributeMaxDynamicSharedMemorySize, 137216);

    hipLaunchKernelGGL(k_prep, dim3(354), dim3(256), 0, stream,
                       dW1, db1, rW1, rb1, rel, dW2, rW2, vW, vb, oW,
                       WnTg, WcTg, VTg, preg, vboWg, w2g);
    hipLaunchKernelGGL(k_ln1, dim3(8192), dim3(256), 0, stream,
                       tok, ln1g, ln1b, norm);
    hipLaunchKernelGGL(k_edge, dim3(256), dim3(512), 137216, stream,
                       tok, ln2g, ln2b, norm, WnTg, WcTg, VTg, preg, vboWg, w2g,
                       db2, rb2, gm, lm, bi, ob, out);
}

// Round 3
// 209.817 us; speedup vs baseline: 1.5948x; 1.0645x over previous
//
#include <hip/hip_runtime.h>

// ---------------------------------------------------------------------------
// EMLLocalMessageBlock on MI355X — round 3.
//   x@W1 = center@(W1a+W1c) + nbhd@(W1b-W1c) + rel@W1d + b1
//   update = [Sum_n g_n (A_n @ VoW)]/mass + (vb@oW)*(sg/mass) + ob
// K-permutation (torch-reshape scramble): slot k'=16r+t <-> c2 = r+9t;
// per (n2,r): shift n=(2*n2+r)%9, channels c=c0+t, c0=(n2*128+r)/9.
// All LDS tiles use row stride AW=152 elems (304 B = 76 dw = 12 mod 32:
// ds_read_b128 lanes 0..7 tile all 8 bank-groups -> conflict-free).
// ---------------------------------------------------------------------------

#define USHORT unsigned short
#define AW 152

typedef __attribute__((ext_vector_type(8)))  __bf16 v8bf;
typedef __attribute__((ext_vector_type(8)))  USHORT v8u;
typedef __attribute__((ext_vector_type(16))) float  v16f;

__device__ __forceinline__ USHORT f2bf(float f) {
    unsigned v; __builtin_memcpy(&v, &f, 4);
    v += 0x7FFFu + ((v >> 16) & 1u);
    return (USHORT)(v >> 16);
}

// ---------------------------------------------------------------------------
// k_setup: blocks [0,354) = weight prep, blocks [354,8546) = LN1.
// ---------------------------------------------------------------------------
__global__ __launch_bounds__(256) void k_setup(
    const float* __restrict__ tok, const float* __restrict__ ln1g,
    const float* __restrict__ ln1b,
    const float* __restrict__ dW1, const float* __restrict__ db1,
    const float* __restrict__ rW1, const float* __restrict__ rb1,
    const float* __restrict__ rel, const float* __restrict__ dW2,
    const float* __restrict__ rW2, const float* __restrict__ vW,
    const float* __restrict__ vb,  const float* __restrict__ oW,
    USHORT* __restrict__ norm,
    USHORT* __restrict__ WnTg, USHORT* __restrict__ WcTg, USHORT* __restrict__ VTg,
    float* __restrict__ preg, float* __restrict__ vboWg, float* __restrict__ w2g)
{
    const int blk = blockIdx.x, t = threadIdx.x;
    if (blk >= 354) {                     // ---- LN1 ----
        const int p = (blk - 354) * 4 + (t >> 6);
        const int lane = t & 63;
        const float2 x = ((const float2*)(tok + (size_t)p * 128))[lane];
        float s = x.x + x.y;
        for (int m = 1; m < 64; m <<= 1) s += __shfl_xor(s, m);
        const float mean = s * (1.f / 128.f);
        const float d0 = x.x - mean, d1 = x.y - mean;
        float q = d0 * d0 + d1 * d1;
        for (int m = 1; m < 64; m <<= 1) q += __shfl_xor(q, m);
        const float rstd = rsqrtf(q * (1.f / 128.f) + 1e-5f);
        const float2 gg = ((const float2*)ln1g)[lane], bb = ((const float2*)ln1b)[lane];
        ((unsigned*)norm)[(size_t)p * 64 + lane] =
            (unsigned)f2bf(d0 * rstd * gg.x + bb.x) |
            ((unsigned)f2bf(d1 * rstd * gg.y + bb.y) << 16);
        return;
    }
    if (blk < 72) {                       // VTg [128][144] = perm(vW@oW)^T
        int idx = blk * 256 + t;
        int n = ((idx >> 4) * 7282) >> 16;
        int k = idx - n * 144;
        int r = k >> 4, tt = k & 15, c2 = r + 9 * tt;
        float acc = 0.f;
        if (c2 < 128)
            for (int j = 0; j < 128; ++j) acc += vW[c2 * 128 + j] * oW[j * 128 + n];
        VTg[idx] = f2bf(acc);
    } else if (blk < 216) {               // WnTg [256][144] = perm(W1b-W1c)^T
        int idx = (blk - 72) * 256 + t;
        int n = ((idx >> 4) * 7282) >> 16;
        int k = idx - n * 144;
        int r = k >> 4, tt = k & 15, c2 = r + 9 * tt;
        int col = n & 127;
        const float* W = (n < 128) ? dW1 : rW1;
        float val = 0.f;
        if (c2 < 128) val = W[(128 + c2) * 128 + col] - W[(256 + c2) * 128 + col];
        WnTg[idx] = f2bf(val);
    } else if (blk < 344) {               // WcTg [256][128] = (W1a+W1c)^T
        int idx = (blk - 216) * 256 + t;
        int n = idx >> 7, c = idx & 127, col = n & 127;
        const float* W = (n < 128) ? dW1 : rW1;
        WcTg[idx] = f2bf(W[c * 128 + col] + W[(256 + c) * 128 + col]);
    } else if (blk < 353) {               // preg[9][256] = rel@W1d + b1
        int n2 = blk - 344; int h = t;
        float acc;
        if (h < 128) {
            acc = db1[h];
            for (int r = 0; r < 8; ++r) acc += rel[n2 * 8 + r] * dW1[(384 + r) * 128 + h];
        } else {
            int hh = h - 128;
            acc = rb1[hh];
            for (int r = 0; r < 8; ++r) acc += rel[n2 * 8 + r] * rW1[(384 + r) * 128 + hh];
        }
        preg[n2 * 256 + h] = acc;
    } else {
        if (t < 128) {
            float acc = 0.f;
            for (int j = 0; j < 128; ++j) acc += vb[j] * oW[j * 128 + t];
            vboWg[t] = acc;
            w2g[t] = dW2[t];
            w2g[128 + t] = rW2[t];
        }
    }
}

// ---------------------------------------------------------------------------
// gather one n2 A-tile into LDS (permuted-K layout), coalesced global reads
// ---------------------------------------------------------------------------
__device__ __forceinline__ void gather_tile(
    USHORT* __restrict__ Ash, const USHORT* __restrict__ nb,
    int n2, int y, int bI, int tid)
{
    const int x = tid >> 2, q = tid & 3;
    #pragma unroll
    for (int r = 0; r < 9; ++r) {
        int u = 2 * n2 + r;
        int n = (u >= 18) ? (u - 18) : ((u >= 9) ? (u - 9) : u);
        int v = n2 * 128 + r;
        int c0 = (v * 7282) >> 16;                 // v/9
        int dyq = (n * 22) >> 6;                   // n/3
        int dx = n - 3 * dyq - 1;
        int dy = dyq - 1;
        int sy = y + dy, sx = x + dx;
        bool ok = ((unsigned)sy < 128u) && ((unsigned)sx < 128u);
        int e0 = (c0 & ~1) + 4 * q;
        size_t gidx = ((size_t)((bI * 128 + (ok ? sy : 0)) * 128 + (ok ? sx : 0))) * 128 + e0;
        const unsigned* gp = (const unsigned*)nb + (gidx >> 1);
        unsigned dw0 = gp[0], dw1 = gp[1];
        unsigned nxt = (unsigned)__shfl_down((int)dw0, 1);   // only feeds slot15 (zero-wt)
        unsigned o0, o1;
        if (c0 & 1) { o0 = (dw0 >> 16) | (dw1 << 16); o1 = (dw1 >> 16) | (nxt << 16); }
        else        { o0 = dw0;                       o1 = dw1; }
        if (!ok) { o0 = 0u; o1 = 0u; }
        *(uint2*)(Ash + x * AW + 16 * r + 4 * q) = make_uint2(o0, o1);
    }
}

// ---------------------------------------------------------------------------
// k_edge: 256 blocks (one image row each), 512 threads = 8 waves = 2M x 4N.
// MFMA 32x32x16 bf16; C/D: col=lane&31, row=(reg&3)+8*(reg>>2)+4*(lane>>5).
// LDS 158720 B: Wsh[256][152] | Ash[128][152] | VTl[128][152] | w2L | sums
// ---------------------------------------------------------------------------
__global__ __launch_bounds__(512, 2) void k_edge(
    const float* __restrict__ tok, const float* __restrict__ ln2g,
    const float* __restrict__ ln2b, const USHORT* __restrict__ nb,
    const USHORT* __restrict__ WnTg, const USHORT* __restrict__ WcTg,
    const USHORT* __restrict__ VTg, const float* __restrict__ preg,
    const float* __restrict__ vboWg, const float* __restrict__ w2g,
    const float* __restrict__ db2p, const float* __restrict__ rb2p,
    const float* __restrict__ gmp, const float* __restrict__ lmp,
    const float* __restrict__ bip, const float* __restrict__ obp,
    float* __restrict__ out)
{
    extern __shared__ char smem[];
    USHORT* Wsh  = (USHORT*)smem;                    // [256][152] = 77824
    USHORT* Ash  = (USHORT*)(smem + 77824);          // [128][152] = 38912
    USHORT* VTl  = (USHORT*)(smem + 116736);         // [128][152] = 38912
    float*  w2L  = (float*)(smem + 155648);          // 1024
    float*  dsum = (float*)(smem + 156672);
    float*  rsum = (float*)(smem + 157184);
    float*  gateL= (float*)(smem + 157696);
    float*  sgL  = (float*)(smem + 158208);          // end 158720
    float*  updF = (float*)smem;                     // final alias (64 KB)

    const int tid = threadIdx.x;
    const int lane = tid & 63, wave = tid >> 6, hi = lane >> 5, l31 = lane & 31;
    const int mw = wave & 1, nw = wave >> 1;
    const int blk = blockIdx.x;
    const int bI = blk >> 7;
    const int y = ((blk & 7) << 4) | ((blk >> 3) & 15);   // XCD band swizzle
    const int p0 = (bI * 128 + y) * 128;

    // ---- stage Wc + center A + VoW + w2; zero sums ----
    for (int i = tid; i < 4096; i += 512) {
        int n = i >> 4, kv = i & 15;
        *(v8u*)(Wsh + n * AW + kv * 8) = *(const v8u*)(WcTg + n * 128 + kv * 8);
    }
    for (int i = tid; i < 2048; i += 512) {
        int x = i >> 4, kv = i & 15;
        *(v8u*)(Ash + x * AW + kv * 8) = *(const v8u*)(nb + (size_t)(p0 + x) * 128 + kv * 8);
    }
    for (int i = tid; i < 2304; i += 512) {
        int n = (i * 3641) >> 16;                    // i/18
        int kv = i - n * 18;
        *(v8u*)(VTl + n * AW + kv * 8) = *(const v8u*)(VTg + n * 144 + kv * 8);
    }
    if (tid < 256) w2L[tid] = w2g[tid];
    if (tid < 128) { dsum[tid] = 0.f; rsum[tid] = 0.f; sgL[tid] = 0.f; }
    __syncthreads();

    // ---- center GEMM (K=128) ----
    v16f cp[2][2];
    #pragma unroll
    for (int a = 0; a < 2; ++a)
        for (int b = 0; b < 2; ++b)
            for (int e = 0; e < 16; ++e) cp[a][b][e] = 0.f;
    #pragma unroll
    for (int ks = 0; ks < 8; ++ks) {
        v8bf af0 = *(const v8bf*)(Ash + (mw * 64 + l31) * AW + ks * 16 + hi * 8);
        v8bf af1 = *(const v8bf*)(Ash + (mw * 64 + 32 + l31) * AW + ks * 16 + hi * 8);
        v8bf bf0 = *(const v8bf*)(Wsh + (nw * 64 + l31) * AW + ks * 16 + hi * 8);
        v8bf bf1 = *(const v8bf*)(Wsh + (nw * 64 + 32 + l31) * AW + ks * 16 + hi * 8);
        cp[0][0] = __builtin_amdgcn_mfma_f32_32x32x16_bf16(af0, bf0, cp[0][0], 0, 0, 0);
        cp[0][1] = __builtin_amdgcn_mfma_f32_32x32x16_bf16(af0, bf1, cp[0][1], 0, 0, 0);
        cp[1][0] = __builtin_amdgcn_mfma_f32_32x32x16_bf16(af1, bf0, cp[1][0], 0, 0, 0);
        cp[1][1] = __builtin_amdgcn_mfma_f32_32x32x16_bf16(af1, bf1, cp[1][1], 0, 0, 0);
    }
    __syncthreads();

    // ---- stage permuted Wn over Wc; first gather ----
    for (int i = tid; i < 4608; i += 512) {
        int n = (i * 3641) >> 16;
        int kv = i - n * 18;
        *(v8u*)(Wsh + n * AW + kv * 8) = *(const v8u*)(WnTg + n * 144 + kv * 8);
    }
    gather_tile(Ash, nb, 0, y, bI, tid);

    const float gmv = gmp[0], lmv = lmp[0], biv = bip[0];
    const float db2v = db2p[0], rb2v = rb2p[0];
    const float wv0 = w2L[nw * 64 + l31];
    const float wv1 = w2L[nw * 64 + 32 + l31];

    v16f acc3[2];
    #pragma unroll
    for (int a = 0; a < 2; ++a)
        for (int e = 0; e < 16; ++e) acc3[a][e] = 0.f;

    for (int n2 = 0; n2 < 9; ++n2) {
        const float pv0 = preg[n2 * 256 + nw * 64 + l31];
        const float pv1 = preg[n2 * 256 + nw * 64 + 32 + l31];
        __syncthreads();                  // C: Ash(n2) ready
        // ---- edge GEMM: acc = cp + A_{n2} @ Wn (K'=144) ----
        v16f acc[2][2];
        #pragma unroll
        for (int a = 0; a < 2; ++a)
            for (int b = 0; b < 2; ++b) acc[a][b] = cp[a][b];
        #pragma unroll
        for (int ks = 0; ks < 9; ++ks) {
            v8bf af0 = *(const v8bf*)(Ash + (mw * 64 + l31) * AW + ks * 16 + hi * 8);
            v8bf af1 = *(const v8bf*)(Ash + (mw * 64 + 32 + l31) * AW + ks * 16 + hi * 8);
            v8bf bf0 = *(const v8bf*)(Wsh + (nw * 64 + l31) * AW + ks * 16 + hi * 8);
            v8bf bf1 = *(const v8bf*)(Wsh + (nw * 64 + 32 + l31) * AW + ks * 16 + hi * 8);
            acc[0][0] = __builtin_amdgcn_mfma_f32_32x32x16_bf16(af0, bf0, acc[0][0], 0, 0, 0);
            acc[0][1] = __builtin_amdgcn_mfma_f32_32x32x16_bf16(af0, bf1, acc[0][1], 0, 0, 0);
            acc[1][0] = __builtin_amdgcn_mfma_f32_32x32x16_bf16(af1, bf0, acc[1][0], 0, 0, 0);
            acc[1][1] = __builtin_amdgcn_mfma_f32_32x32x16_bf16(af1, bf1, acc[1][1], 0, 0, 0);
        }
        // ---- epilogue: gelu(h)·w2, shfl-reduce over l31, atomic per row ----
        #pragma unroll
        for (int mt = 0; mt < 2; ++mt) {
            float part[16];
            #pragma unroll
            for (int rr = 0; rr < 16; ++rr) {
                float h0 = acc[mt][0][rr] + pv0;
                float h1 = acc[mt][1][rr] + pv1;
                float s0 = __builtin_amdgcn_rcpf(1.f + __expf(-1.702f * h0));
                float s1 = __builtin_amdgcn_rcpf(1.f + __expf(-1.702f * h1));
                part[rr] = h0 * s0 * wv0 + h1 * s1 * wv1;
            }
            #pragma unroll
            for (int m = 1; m < 32; m <<= 1) {
                #pragma unroll
                for (int rr = 0; rr < 16; ++rr) part[rr] += __shfl_xor(part[rr], m);
            }
            if (l31 == 0) {
                float* tgt = (nw < 2) ? dsum : rsum;
                #pragma unroll
                for (int rr = 0; rr < 16; ++rr) {
                    int row = mw * 64 + mt * 32 + (rr & 3) + 8 * (rr >> 2) + 4 * hi;
                    atomicAdd(&tgt[row], part[rr]);
                }
            }
        }
        // ---- message GEMM: P = A_{n2} @ VoW (N=128, per-wave 32-col slice) ----
        v16f P[2];
        #pragma unroll
        for (int a = 0; a < 2; ++a)
            for (int e = 0; e < 16; ++e) P[a][e] = 0.f;
        #pragma unroll
        for (int ks = 0; ks < 9; ++ks) {
            v8bf af0 = *(const v8bf*)(Ash + (mw * 64 + l31) * AW + ks * 16 + hi * 8);
            v8bf af1 = *(const v8bf*)(Ash + (mw * 64 + 32 + l31) * AW + ks * 16 + hi * 8);
            v8bf vf  = *(const v8bf*)(VTl + (nw * 32 + l31) * AW + ks * 16 + hi * 8);
            P[0] = __builtin_amdgcn_mfma_f32_32x32x16_bf16(af0, vf, P[0], 0, 0, 0);
            P[1] = __builtin_amdgcn_mfma_f32_32x32x16_bf16(af1, vf, P[1], 0, 0, 0);
        }
        __syncthreads();                  // A: sums final, Ash reads complete
        if (n2 < 8) gather_tile(Ash, nb, n2 + 1, y, bI, tid);
        if (tid < 128) {
            float d = dsum[tid] + db2v, rr = rsum[tid] + rb2v;
            float sp = fmaxf(rr, 0.f) + log1pf(__expf(-fabsf(rr)));
            float e = gmv * d / (lmv * sp + 1e-6f) + biv;
            e = fminf(fmaxf(e, -3.f), 3.f);
            float gt = 1.f / (1.f + __expf(-e));
            gateL[tid] = gt; sgL[tid] += gt;
            dsum[tid] = 0.f; rsum[tid] = 0.f;
        }
        __syncthreads();                  // B: gate ready
        // ---- acc3 += g ⊙ P (broadcast float4 gate reads) ----
        #pragma unroll
        for (int mt = 0; mt < 2; ++mt) {
            const float4* gq = (const float4*)&gateL[mw * 64 + mt * 32 + 4 * hi];
            float4 ga = gq[0], gb = gq[2], gc = gq[4], gd = gq[6];
            float gs[16] = {ga.x, ga.y, ga.z, ga.w, gb.x, gb.y, gb.z, gb.w,
                            gc.x, gc.y, gc.z, gc.w, gd.x, gd.y, gd.z, gd.w};
            #pragma unroll
            for (int rr = 0; rr < 16; ++rr) acc3[mt][rr] += gs[rr] * P[mt][rr];
        }
    }

    // ---- final: mass, update, LN2 ----
    if (tid < 128) {
        float s = sgL[tid];
        float m = fmaxf(s, 1e-6f);
        dsum[tid] = 1.f / m;     // 1/mass
        rsum[tid] = s / m;       // sg/mass
    }
    __syncthreads();

    {
        const int colc = nw * 32 + l31;
        const float vbw = vboWg[colc], obv = obp[colc];
        #pragma unroll
        for (int mt = 0; mt < 2; ++mt) {
            const int base = mw * 64 + mt * 32 + 4 * hi;
            const float4* iq = (const float4*)&dsum[base];
            const float4* sq = (const float4*)&rsum[base];
            float4 ia = iq[0], ib = iq[2], ic = iq[4], id = iq[6];
            float4 sa = sq[0], sb = sq[2], sc = sq[4], sd = sq[6];
            float iv[16] = {ia.x, ia.y, ia.z, ia.w, ib.x, ib.y, ib.z, ib.w,
                            ic.x, ic.y, ic.z, ic.w, id.x, id.y, id.z, id.w};
            float sv[16] = {sa.x, sa.y, sa.z, sa.w, sb.x, sb.y, sb.z, sb.w,
                            sc.x, sc.y, sc.z, sc.w, sd.x, sd.y, sd.z, sd.w};
            #pragma unroll
            for (int rr = 0; rr < 16; ++rr) {
                int row = base + (rr & 3) + 8 * (rr >> 2);
                updF[row * 128 + colc] = acc3[mt][rr] * iv[rr] + vbw * sv[rr] + obv;
            }
        }
    }
    __syncthreads();

    const float g20 = ln2g[lane], g21 = ln2g[lane + 64];
    const float b20 = ln2b[lane], b21 = ln2b[lane + 64];
    for (int q2 = 0; q2 < 16; ++q2) {
        int p = wave * 16 + q2;
        size_t gp = (size_t)(p0 + p) * 128;
        float x0 = tok[gp + lane]      + updF[p * 128 + lane];
        float x1 = tok[gp + lane + 64] + updF[p * 128 + lane + 64];
        float s = x0 + x1;
        for (int m = 1; m < 64; m <<= 1) s += __shfl_xor(s, m);
        float mean = s * (1.f / 128.f);
        float d0 = x0 - mean, d1 = x1 - mean;
        float qq = d0 * d0 + d1 * d1;
        for (int m = 1; m < 64; m <<= 1) qq += __shfl_xor(qq, m);
        float rstd = rsqrtf(qq * (1.f / 128.f) + 1e-5f);
        out[gp + lane]      = d0 * rstd * g20 + b20;
        out[gp + lane + 64] = d1 * rstd * g21 + b21;
    }
}

// ---------------------------------------------------------------------------
extern "C" void kernel_launch(void* const* d_in, const int* in_sizes, int n_in,
                              void* d_out, int out_size, void* d_ws, size_t ws_size,
                              hipStream_t stream) {
    const float* tok  = (const float*)d_in[0];
    const float* ln1g = (const float*)d_in[1];
    const float* ln1b = (const float*)d_in[2];
    const float* ln2g = (const float*)d_in[3];
    const float* ln2b = (const float*)d_in[4];
    const float* rel  = (const float*)d_in[5];
    const float* dW1  = (const float*)d_in[6];
    const float* db1  = (const float*)d_in[7];
    const float* dW2  = (const float*)d_in[8];
    const float* db2  = (const float*)d_in[9];
    const float* rW1  = (const float*)d_in[10];
    const float* rb1  = (const float*)d_in[11];
    const float* rW2  = (const float*)d_in[12];
    const float* rb2  = (const float*)d_in[13];
    const float* vW   = (const float*)d_in[14];
    const float* vb   = (const float*)d_in[15];
    const float* oW   = (const float*)d_in[16];
    const float* ob   = (const float*)d_in[17];
    const float* gm   = (const float*)d_in[18];
    const float* lm   = (const float*)d_in[19];
    const float* bi   = (const float*)d_in[20];
    float* out = (float*)d_out;

    char* w = (char*)d_ws;
    USHORT* norm = (USHORT*)w; w += 8388608;   // [32768][128] bf16 (gather may
                                               //  over-read 2 elems into WnTg: finite)
    USHORT* WnTg = (USHORT*)w; w += 73728;     // [256][144] bf16, permuted+zero-pad
    USHORT* WcTg = (USHORT*)w; w += 65536;     // [256][128] bf16
    USHORT* VTg  = (USHORT*)w; w += 36864;     // [128][144] bf16, permuted+zero-pad
    float*  preg = (float*)w;  w += 9216;      // [9][256] f32
    float*  vboWg= (float*)w;  w += 512;       // [128] f32
    float*  w2g  = (float*)w;  w += 1024;      // [256] f32

    hipFuncSetAttribute((const void*)k_edge,
                        hipFuncAttributeMaxDynamicSharedMemorySize, 158720);

    hipLaunchKernelGGL(k_setup, dim3(8546), dim3(256), 0, stream,
                       tok, ln1g, ln1b, dW1, db1, rW1, rb1, rel, dW2, rW2,
                       vW, vb, oW, norm, WnTg, WcTg, VTg, preg, vboWg, w2g);
    hipLaunchKernelGGL(k_edge, dim3(256), dim3(512), 158720, stream,
                       tok, ln2g, ln2b, norm, WnTg, WcTg, VTg, preg, vboWg, w2g,
                       db2, rb2, gm, lm, bi, ob, out);
}